// Round 1
// baseline (152.995 us; speedup 1.0000x reference)
//
#include <hip/hip_runtime.h>

// Problem constants (from reference): B=4, L=2048, C=64, D=4
#define BB 4
#define LL 2048
#define CC 64
#define DD 4
#define NN (CC * DD * DD)   // 1024 chains per batch, contiguous inner dim
#define GG 32               // time chunks
#define TT (LL / GG)        // 64 timesteps per chunk

// Chain n in [0,1024): n = c*16 + i*4 + j. A index within (b,t): n>>2 (c*4+i).
// X flat index: (b*L + t)*1024 + n. Out: float2 at (b*L + t)*1024 + n  -> [...,2].

// Phase 1: per (b, g, n) compute chunk aggregate (p, s):
//   p = prod A over chunk, s = scan-combine of X over chunk (zero initial).
__global__ __launch_bounds__(256) void pscan_phase1(
    const float* __restrict__ A_re, const float* __restrict__ A_im,
    const float* __restrict__ X_re, const float* __restrict__ X_im,
    float4* __restrict__ agg) {
  int u = blockIdx.x * 256 + threadIdx.x;      // [0, B*G*N)
  int n  = u & (NN - 1);
  int bg = u >> 10;                             // b*G + g
  int g  = bg & (GG - 1);
  int b  = bg >> 5;
  int t0 = g * TT;
  long baseA = (long)(b * LL + t0) * (CC * DD) + (n >> 2);
  long baseX = (long)(b * LL + t0) * NN + n;

  float p_re = 1.f, p_im = 0.f, s_re = 0.f, s_im = 0.f;
#pragma unroll 8
  for (int t = 0; t < TT; ++t) {
    float are = A_re[baseA + (long)t * (CC * DD)];
    float aim = A_im[baseA + (long)t * (CC * DD)];
    float xre = X_re[baseX + (long)t * NN];
    float xim = X_im[baseX + (long)t * NN];
    float nsre = are * s_re - aim * s_im + xre;
    float nsim = are * s_im + aim * s_re + xim;
    float npre = are * p_re - aim * p_im;
    float npim = are * p_im + aim * p_re;
    s_re = nsre; s_im = nsim; p_re = npre; p_im = npim;
  }
  agg[u] = make_float4(p_re, p_im, s_re, s_im);
}

// Phase 2: one thread per (b, n): in-place exclusive scan of aggregates over g.
// combine(run=(rp,rs), v=(vp,vs)) = (vp*rp, vp*rs + vs)   (run is earlier)
__global__ __launch_bounds__(256) void pscan_phase2(float4* __restrict__ agg) {
  int u = blockIdx.x * 256 + threadIdx.x;      // [0, B*N)
  int n = u & (NN - 1);
  int b = u >> 10;
  float rp_re = 1.f, rp_im = 0.f, rs_re = 0.f, rs_im = 0.f;
  for (int g = 0; g < GG; ++g) {
    long idx = (long)(b * GG + g) * NN + n;
    float4 v = agg[idx];
    agg[idx] = make_float4(rp_re, rp_im, rs_re, rs_im);
    float np_re = v.x * rp_re - v.y * rp_im;
    float np_im = v.x * rp_im + v.y * rp_re;
    float ns_re = v.x * rs_re - v.y * rs_im + v.z;
    float ns_im = v.x * rs_im + v.y * rs_re + v.w;
    rp_re = np_re; rp_im = np_im; rs_re = ns_re; rs_im = ns_im;
  }
}

// Phase 3: seed y with carry's s-component, re-run recurrence, write out.
__global__ __launch_bounds__(256) void pscan_phase3(
    const float* __restrict__ A_re, const float* __restrict__ A_im,
    const float* __restrict__ X_re, const float* __restrict__ X_im,
    const float4* __restrict__ carry, float2* __restrict__ out) {
  int u = blockIdx.x * 256 + threadIdx.x;      // [0, B*G*N)
  int n  = u & (NN - 1);
  int bg = u >> 10;
  int g  = bg & (GG - 1);
  int b  = bg >> 5;
  int t0 = g * TT;
  long baseA = (long)(b * LL + t0) * (CC * DD) + (n >> 2);
  long baseX = (long)(b * LL + t0) * NN + n;

  float4 cv = carry[u];
  float y_re = cv.z, y_im = cv.w;
#pragma unroll 8
  for (int t = 0; t < TT; ++t) {
    float are = A_re[baseA + (long)t * (CC * DD)];
    float aim = A_im[baseA + (long)t * (CC * DD)];
    float xre = X_re[baseX + (long)t * NN];
    float xim = X_im[baseX + (long)t * NN];
    float ny_re = are * y_re - aim * y_im + xre;
    float ny_im = are * y_im + aim * y_re + xim;
    y_re = ny_re; y_im = ny_im;
    out[baseX + (long)t * NN] = make_float2(y_re, y_im);
  }
}

extern "C" void kernel_launch(void* const* d_in, const int* in_sizes, int n_in,
                              void* d_out, int out_size, void* d_ws, size_t ws_size,
                              hipStream_t stream) {
  const float* A_re = (const float*)d_in[0];
  const float* A_im = (const float*)d_in[1];
  const float* X_re = (const float*)d_in[2];
  const float* X_im = (const float*)d_in[3];
  float2* out = (float2*)d_out;
  float4* agg = (float4*)d_ws;   // needs B*G*N*16 = 2 MiB of workspace

  const int total = BB * GG * NN;              // 131072... (4*32*1024 = 131072)
  pscan_phase1<<<total / 256, 256, 0, stream>>>(A_re, A_im, X_re, X_im, agg);
  pscan_phase2<<<(BB * NN) / 256, 256, 0, stream>>>(agg);
  pscan_phase3<<<total / 256, 256, 0, stream>>>(A_re, A_im, X_re, X_im, agg, out);
}